// Round 4
// baseline (279.532 us; speedup 1.0000x reference)
//
#include <hip/hip_runtime.h>
#include <cstdint>

#define S_LEN   2048
#define BATCH   4
#define NCH     4096                    // B*NH*HD channels
#define PLANE   ((size_t)S_LEN * NCH)   // per-gate plane: 8,388,608 elems
#define CHUNK   32
#define NCHUNK  64
#define SN      ((size_t)NCHUNK * NCH)  // 262144 summary slots
#define EPS     1e-8f

using bf16x8 = __attribute__((ext_vector_type(8))) short;
using f32x4  = __attribute__((ext_vector_type(4))) float;
typedef unsigned short u16;

__device__ __forceinline__ short f2bf(float f) {
  uint32_t u = __builtin_bit_cast(uint32_t, f);
  u += 0x7fffu + ((u >> 16) & 1u);
  return (short)(u >> 16);
}
__device__ __forceinline__ float bf2f(u16 u) {
  return __builtin_bit_cast(float, (uint32_t)u << 16);
}
// LDS-only barrier: orders ds ops without draining in-flight global loads
// (compiler's __syncthreads emits s_waitcnt vmcnt(0) which kills prefetch).
__device__ __forceinline__ void lds_barrier() {
  asm volatile("s_waitcnt lgkmcnt(0)\n\ts_barrier" ::: "memory");
}

// ---------------------------------------------------------------------------
// Kernel 1: gate projection. Block = 1024 thr (16 waves) owns one (g,h) x
// 256 rows x 256 cols. A staged via double-buffered bf16 LDS (stride 272);
// register prefetch depth 2; ALL stores deferred to a barrier-free epilogue
// (acc for 16 tiles held in 64 VGPRs). lds_barrier() keeps the depth-2
// global prefetch in flight across tile boundaries.
// ---------------------------------------------------------------------------
__global__ __launch_bounds__(1024) void gates_gemm4(
    const float* __restrict__ x, const float* __restrict__ W,
    const float* __restrict__ bias,
    u16* __restrict__ gz16, float* __restrict__ gi, float* __restrict__ gf,
    u16* __restrict__ go16) {
  __shared__ u16 As[2][16 * 272];   // 2 x 8704 B

  const int gh  = blockIdx.x;          // g*4+h
  const int rg  = blockIdx.y;          // 0..31, 256 rows each
  const int g   = gh >> 2, hh = gh & 3;
  const int tid = threadIdx.x;
  const int wave = tid >> 6, lane = tid & 63;
  const int l16 = lane & 15, quad = lane >> 4;
  const int n0  = wave * 16;
  const int row0 = rg * 256;

  // B fragments for this wave's 16-col strip (held all kernel)
  bf16x8 Bf[8];
  {
    const float* wp = W + ((size_t)gh << 16) + (n0 + l16) * 256 + quad * 8;
#pragma unroll
    for (int kt = 0; kt < 8; ++kt) {
      float4 w0 = *(const float4*)(wp + kt * 32);
      float4 w1 = *(const float4*)(wp + kt * 32 + 4);
      bf16x8 b;
      b[0] = f2bf(w0.x); b[1] = f2bf(w0.y); b[2] = f2bf(w0.z); b[3] = f2bf(w0.w);
      b[4] = f2bf(w1.x); b[5] = f2bf(w1.y); b[6] = f2bf(w1.z); b[7] = f2bf(w1.w);
      Bf[kt] = b;
    }
  }
  const float bv = bias[gh * 256 + n0 + l16];

  // staging: thread tid loads float4 #tid of the 16x256 tile
  const int sr = tid >> 6, sc = tid & 63;
  const float* sbase = x + (size_t)(row0 + sr) * 4096 + g * 1024 + hh * 256 + sc * 4;

  auto swrite = [&](int buf, float4 v) {
    ushort4 u;
    u.x = (u16)f2bf(v.x); u.y = (u16)f2bf(v.y);
    u.z = (u16)f2bf(v.z); u.w = (u16)f2bf(v.w);
    *(ushort4*)&As[buf][sr * 272 + sc * 4] = u;
  };

  float4 pf[2];
  pf[0] = *(const float4*)(sbase);
  pf[1] = *(const float4*)(sbase + (size_t)16 * 4096);
  swrite(0, pf[0]);
  lds_barrier();

  f32x4 acc[16];
#pragma unroll
  for (int t = 0; t < 16; ++t) acc[t] = (f32x4){0.f, 0.f, 0.f, 0.f};

#pragma unroll
  for (int t = 0; t < 16; ++t) {
    if (t + 2 < 16) pf[t & 1] = *(const float4*)(sbase + (size_t)(t + 2) * 16 * 4096);

#pragma unroll
    for (int kt = 0; kt < 8; ++kt) {
      bf16x8 a = *(const bf16x8*)&As[t & 1][l16 * 272 + kt * 32 + quad * 8];
      acc[t] = __builtin_amdgcn_mfma_f32_16x16x32_bf16(a, Bf[kt], acc[t], 0, 0, 0);
    }

    if (t + 1 < 16) {
      swrite((t + 1) & 1, pf[(t + 1) & 1]);   // waits only this reg's vmcnt
      lds_barrier();
    }
  }

  // barrier-free store epilogue with fused activations
#pragma unroll
  for (int t = 0; t < 16; ++t) {
#pragma unroll
    for (int rr = 0; rr < 4; ++rr) {
      int rowi = row0 + t * 16 + quad * 4 + rr;
      int sx = rowi & (S_LEN - 1);
      int bx = rowi >> 11;
      size_t idx = (size_t)sx * NCH + bx * 1024 + hh * 256 + n0 + l16;
      float v = acc[t][rr] + bv;
      if (g == 1)      gi[idx] = v;
      else if (g == 2) gf[idx] = v;
      else if (g == 0) {
        float tz = 1.f - 2.f * __builtin_amdgcn_rcpf(1.f + __expf(2.f * v));
        gz16[idx] = (u16)f2bf(tz);
      } else {
        float s = __builtin_amdgcn_rcpf(1.f + __expf(-v));
        go16[idx] = (u16)f2bf(s);
      }
    }
  }
}

// ---------------------------------------------------------------------------
// Kernel 2: pass 1 — per (channel, 32-step chunk) locally-stabilized
// summaries. 2-group-ahead prefetch (3 rotating buffers).
// ---------------------------------------------------------------------------
__global__ __launch_bounds__(256, 4) void scan_pass1(
    const u16* __restrict__ gz16, const float* __restrict__ gi,
    const float* __restrict__ gf, float* __restrict__ sums) {
  const int t  = blockIdx.x * 256 + threadIdx.x;   // 262144
  const int ch = t & (NCH - 1);
  const int ck = t >> 12;                           // 0..63
  const size_t base = (size_t)ck * CHUNK * NCH + ch;

  float A = 0.f, Bv = -1e30f, D = 0.f, Dn = 0.f;

  u16 zb[3][8]; float ib[3][8], fb[3][8];

  auto loadg = [&](int buf, int grp) {
#pragma unroll
    for (int j = 0; j < 8; ++j) {
      size_t off = base + (size_t)(grp * 8 + j) * NCH;
      zb[buf][j] = gz16[off]; ib[buf][j] = gi[off]; fb[buf][j] = gf[off];
    }
  };

  loadg(0, 0);
  loadg(1, 1);

#pragma unroll
  for (int grp = 0; grp < 4; ++grp) {
    if (grp + 2 < 4) loadg((grp + 2) % 3, grp + 2);
    const int b = grp % 3;
#pragma unroll
    for (int j = 0; j < 8; ++j) {
      float z = bf2f(zb[b][j]), i = ib[b][j], f = fb[b][j];
      float Bn = fmaxf(Bv + f, i);
      float e1 = __expf(Bv + f - Bn);
      float e2 = __expf(i - Bn);
      D  = e1 * D + e2 * z;
      Dn = e1 * Dn + e2;
      A += f;
      Bv = Bn;
    }
  }

  const size_t idx = (size_t)ck * NCH + ch;
  sums[idx]          = A;
  sums[SN + idx]     = Bv;
  sums[2 * SN + idx] = D;
  sums[3 * SN + idx] = Dn;
}

// ---------------------------------------------------------------------------
// Kernel 3: pass 2 — wave-parallel Kogge-Stone scan over the 64 chunk
// summaries. One wave per channel (lane = chunk index). Writes entering
// (c,n,m) per chunk.
// ---------------------------------------------------------------------------
__global__ __launch_bounds__(256) void scan_pass2(
    const float* __restrict__ sums, float* __restrict__ ent) {
  const int gt   = blockIdx.x * 256 + threadIdx.x;
  const int ch   = gt >> 6;          // 0..4095
  const int lane = threadIdx.x & 63; // chunk index

  const size_t idx = (size_t)lane * NCH + ch;
  float A = sums[idx], B = sums[SN + idx];
  float D = sums[2 * SN + idx], N = sums[3 * SN + idx];

  // inclusive scan with compose: (earlier)∘(self)
#pragma unroll
  for (int d = 1; d < 64; d <<= 1) {
    float A1 = __shfl_up(A, d, 64);
    float B1 = __shfl_up(B, d, 64);
    float D1 = __shfl_up(D, d, 64);
    float N1 = __shfl_up(N, d, 64);
    if (lane >= d) {
      float Bn = fmaxf(B1 + A, B);
      float s1 = __expf(B1 + A - Bn);
      float s2 = __expf(B - Bn);
      D = s1 * D1 + s2 * D;
      N = s1 * N1 + s2 * N;
      B = Bn;
      A = A1 + A;
    }
  }

  // exclusive prefix for this lane's chunk
  float Ax = __shfl_up(A, 1, 64), Bx = __shfl_up(B, 1, 64);
  float Dx = __shfl_up(D, 1, 64), Nx = __shfl_up(N, 1, 64);
  if (lane == 0) { Ax = 0.f; Bx = -1e30f; Dx = 0.f; Nx = 0.f; }

  // entering state from (c,n,m)=(0,0,0): m=max(Ax,Bx), c=e^{Bx-m}Dx, n=e^{Bx-m}Nx
  float mE = fmaxf(Ax, Bx);
  float sc = __expf(Bx - mE);
  ent[idx]          = sc * Dx;
  ent[SN + idx]     = sc * Nx;
  ent[2 * SN + idx] = mE;
}

// ---------------------------------------------------------------------------
// Kernel 4: pass 3 — read entering state, replay 32 steps of the original
// recurrence, write h. 2-group-ahead prefetch. Last chunk writes finals.
// ---------------------------------------------------------------------------
__global__ __launch_bounds__(256, 4) void scan_pass3(
    const u16* __restrict__ gz16, const float* __restrict__ gi,
    const float* __restrict__ gf, const u16* __restrict__ go16,
    const float* __restrict__ ent, float* __restrict__ out) {
  const int t  = blockIdx.x * 256 + threadIdx.x;
  const int ch = t & (NCH - 1);
  const int ck = t >> 12;

  const size_t idx0 = (size_t)ck * NCH + ch;
  float c = ent[idx0];
  float n = ent[SN + idx0];
  float m = ent[2 * SN + idx0];

  const int b = ch >> 10, d = ch & 1023;
  const size_t base = (size_t)ck * CHUNK * NCH + ch;
  float* hout = out + (size_t)b * (S_LEN * 1024) + (size_t)(ck * CHUNK) * 1024 + d;

  u16 zb[3][8], ob[3][8]; float ib[3][8], fb[3][8];

  auto loadg = [&](int buf, int grp) {
#pragma unroll
    for (int j = 0; j < 8; ++j) {
      size_t off = base + (size_t)(grp * 8 + j) * NCH;
      zb[buf][j] = gz16[off]; ib[buf][j] = gi[off];
      fb[buf][j] = gf[off];   ob[buf][j] = go16[off];
    }
  };

  loadg(0, 0);
  loadg(1, 1);

  float hv = 0.f;
#pragma unroll
  for (int grp = 0; grp < 4; ++grp) {
    if (grp + 2 < 4) loadg((grp + 2) % 3, grp + 2);
    const int bu = grp % 3;
#pragma unroll
    for (int j = 0; j < 8; ++j) {
      float z = bf2f(zb[bu][j]), i = ib[bu][j], f = fb[bu][j], o = bf2f(ob[bu][j]);
      float mn = fmaxf(f + m, i);
      float fh = __expf(f + m - mn);
      float ih = __expf(i - mn);
      c = fh * c + ih * z;
      n = fh * n + ih;
      m = mn;
      hv = o * c * __builtin_amdgcn_rcpf(n + EPS);
      hout[(size_t)(grp * 8 + j) * 1024] = hv;
    }
  }

  if (ck == NCHUNK - 1) {
    float* fin = out + (size_t)BATCH * S_LEN * 1024;   // 8,388,608
    fin[ch]            = hv;
    fin[NCH + ch]      = c;
    fin[2 * NCH + ch]  = n;
    fin[3 * NCH + ch]  = m;
  }
}

extern "C" void kernel_launch(void* const* d_in, const int* in_sizes, int n_in,
                              void* d_out, int out_size, void* d_ws, size_t ws_size,
                              hipStream_t stream) {
  const float* x    = (const float*)d_in[0];   // [4,2048,4096] fp32
  const float* W    = (const float*)d_in[1];   // [4,4,256,256] fp32
  const float* bias = (const float*)d_in[2];   // [4,4,256] fp32
  float* out = (float*)d_out;

  // ws layout: z bf16 | i fp32 | f fp32 | o bf16 | sums 4*SN | ent 3*SN
  u16*   gz16 = (u16*)d_ws;                       // 16.78 MB
  float* gi   = (float*)(gz16 + PLANE);           // 33.55 MB
  float* gf   = gi + PLANE;                       // 33.55 MB
  u16*   go16 = (u16*)(gf + PLANE);               // 16.78 MB
  float* sums = (float*)(go16 + PLANE);           // 4.19 MB
  float* ent  = sums + 4 * SN;                    // 3.15 MB  (total ~108 MB)

  gates_gemm4<<<dim3(16, 32), dim3(1024), 0, stream>>>(x, W, bias, gz16, gi, gf, go16);
  scan_pass1<<<dim3(1024), dim3(256), 0, stream>>>(gz16, gi, gf, sums);
  scan_pass2<<<dim3(1024), dim3(256), 0, stream>>>(sums, ent);
  scan_pass3<<<dim3(1024), dim3(256), 0, stream>>>(gz16, gi, gf, go16, ent, out);
}